// Round 16
// baseline (222.462 us; speedup 1.0000x reference)
//
#include <hip/hip_runtime.h>

typedef unsigned short u16;
typedef unsigned int u32;
typedef __attribute__((ext_vector_type(8))) __bf16 bf16x8;
typedef __attribute__((ext_vector_type(4))) float f32x4;

#define NSEQ 2048
#define NDIM 1024
#define NHEAD 16
#define NTOK 4096
#define NX   4194304   /* NTOK*NDIM */
#define NWEL 1048576   /* NDIM*NDIM */

__device__ __forceinline__ u16 f2bf(float f) {
  unsigned u = __float_as_uint(f);
  return (u16)((u + 0x7fffu + ((u >> 16) & 1u)) >> 16);
}
__device__ __forceinline__ float bf2f(u16 h) {
  return __uint_as_float(((unsigned)h) << 16);
}
__device__ __forceinline__ bf16x8 ld16(const u16* p) {
  int4 v = *reinterpret_cast<const int4*>(p);
  return __builtin_bit_cast(bf16x8, v);
}
__device__ __forceinline__ f32x4 mfma16(bf16x8 a, bf16x8 b, f32x4 c) {
  return __builtin_amdgcn_mfma_f32_16x16x32_bf16(a, b, c, 0, 0, 0);
}
// packed f32x2 -> bf16x2 (RNE), one instruction (m214/m240-verified: lo=src0)
__device__ __forceinline__ u32 cvtpk(float lo, float hi) {
  u32 r;
  asm("v_cvt_pk_bf16_f32 %0, %1, %2" : "=v"(r) : "v"(lo), "v"(hi));
  return r;
}
// 3-input max, single instruction (T17)
__device__ __forceinline__ float max3f(float a, float b, float c) {
  float d;
  asm("v_max3_f32 %0, %1, %2, %3" : "=v"(d) : "v"(a), "v"(b), "v"(c));
  return d;
}
// async global->LDS, 16B per lane; LDS dest = wave-uniform base + lane*16
__device__ __forceinline__ void gload16(const u16* g, u16* l) {
  __builtin_amdgcn_global_load_lds(
      (const __attribute__((address_space(1))) void*)g,
      (__attribute__((address_space(3))) void*)l, 16, 0, 0);
}

// GEMM k-loops stay macro-expanded: round-2 post-mortem showed a function
// boundary around the accumulator array -> SROA failure -> acc in scratch.
// Round-14: single-buffer REGRESSED (in-block dbuf is essential).
// Round-15: fp16 single-product projection FAILED (absmax 472) -- Q,K need
// the 3-product bf16 split. 7 product units is the workload floor.
#define GEMM_PROLOGUE                                                         \
  const int tid = threadIdx.x;                                                \
  const int lane = tid & 63, wid = tid >> 6;                                  \
  const int wm = wid >> 1, wn = wid & 1;                                      \
  const int lr = lane & 15, lg = lane >> 4;                                   \
  const int srow_ = tid >> 2;                                                 \
  const int sch_ = ((tid & 3) ^ ((tid >> 3) & 3)) * 8;                        \
  const int rsw_ = (lg ^ ((lr >> 1) & 3)) * 8;

#define STAGE3(BB, AH, AL, BH, BL, T0, J0, K0)                                \
  {                                                                           \
    u16* bb_ = (BB);                                                          \
    gload16(AH + (size_t)((T0) + srow_) * NDIM + (K0) + sch_, bb_ + tid * 8); \
    gload16(AH + (size_t)((T0) + 64 + srow_) * NDIM + (K0) + sch_,            \
            bb_ + 2048 + tid * 8);                                            \
    gload16(BH + (size_t)((J0) + srow_) * NDIM + (K0) + sch_,                 \
            bb_ + 4096 + tid * 8);                                            \
    gload16(BH + (size_t)((J0) + 64 + srow_) * NDIM + (K0) + sch_,            \
            bb_ + 6144 + tid * 8);                                            \
    gload16(AL + (size_t)((T0) + srow_) * NDIM + (K0) + sch_,                 \
            bb_ + 8192 + tid * 8);                                            \
    gload16(AL + (size_t)((T0) + 64 + srow_) * NDIM + (K0) + sch_,            \
            bb_ + 10240 + tid * 8);                                           \
    gload16(BL + (size_t)((J0) + srow_) * NDIM + (K0) + sch_,                 \
            bb_ + 12288 + tid * 8);                                           \
    gload16(BL + (size_t)((J0) + 64 + srow_) * NDIM + (K0) + sch_,            \
            bb_ + 14336 + tid * 8);                                           \
  }

#define GEMM3_LOOP(AH, AL, BH, BL, T0, J0)                                    \
  STAGE3(lds, AH, AL, BH, BL, T0, J0, 0)                                      \
  __syncthreads();                                                            \
  for (int k0 = 0; k0 < NDIM; k0 += 32) {                                     \
    u16* cb_ = lds + ((k0 >> 5) & 1) * 16384;                                 \
    if (k0 + 32 < NDIM) {                                                     \
      u16* nb_ = lds + ((((k0 >> 5) & 1) ^ 1) * 16384);                       \
      STAGE3(nb_, AH, AL, BH, BL, T0, J0, k0 + 32)                            \
    }                                                                         \
    bf16x8 afh[4], afl[4];                                                    \
    _Pragma("unroll") for (int m = 0; m < 4; m++) {                           \
      int off = (wm * 64 + m * 16 + lr) * 32 + rsw_;                          \
      afh[m] = ld16(cb_ + off);                                               \
      afl[m] = ld16(cb_ + 8192 + off);                                        \
    }                                                                         \
    _Pragma("unroll") for (int n = 0; n < 4; n++) {                           \
      int off = (wn * 64 + n * 16 + lr) * 32 + rsw_;                          \
      bf16x8 bfh = ld16(cb_ + 4096 + off);                                    \
      bf16x8 bfl = ld16(cb_ + 12288 + off);                                   \
      _Pragma("unroll") for (int m = 0; m < 4; m++) {                         \
        acc[m][n] = mfma16(afh[m], bfh, acc[m][n]);                           \
        acc[m][n] = mfma16(afh[m], bfl, acc[m][n]);                           \
        acc[m][n] = mfma16(afl[m], bfh, acc[m][n]);                           \
      }                                                                       \
    }                                                                         \
    __syncthreads();                                                          \
  }

#define STAGE1(BB, AH, BH, T0, J0, K0)                                        \
  {                                                                           \
    u16* bb_ = (BB);                                                          \
    gload16(AH + (size_t)((T0) + srow_) * NDIM + (K0) + sch_, bb_ + tid * 8); \
    gload16(AH + (size_t)((T0) + 64 + srow_) * NDIM + (K0) + sch_,            \
            bb_ + 2048 + tid * 8);                                            \
    gload16(BH + (size_t)((J0) + srow_) * NDIM + (K0) + sch_,                 \
            bb_ + 4096 + tid * 8);                                            \
    gload16(BH + (size_t)((J0) + 64 + srow_) * NDIM + (K0) + sch_,            \
            bb_ + 6144 + tid * 8);                                            \
  }

#define GEMM1_LOOP(AH, BH, T0, J0)                                            \
  STAGE1(lds, AH, BH, T0, J0, 0)                                              \
  __syncthreads();                                                            \
  for (int k0 = 0; k0 < NDIM; k0 += 32) {                                     \
    u16* cb_ = lds + ((k0 >> 5) & 1) * 8192;                                  \
    if (k0 + 32 < NDIM) {                                                     \
      u16* nb_ = lds + ((((k0 >> 5) & 1) ^ 1) * 8192);                        \
      STAGE1(nb_, AH, BH, T0, J0, k0 + 32)                                    \
    }                                                                         \
    bf16x8 afh[4];                                                            \
    _Pragma("unroll") for (int m = 0; m < 4; m++) {                           \
      int off = (wm * 64 + m * 16 + lr) * 32 + rsw_;                          \
      afh[m] = ld16(cb_ + off);                                               \
    }                                                                         \
    _Pragma("unroll") for (int n = 0; n < 4; n++) {                           \
      int off = (wn * 64 + n * 16 + lr) * 32 + rsw_;                          \
      bf16x8 bfh = ld16(cb_ + 4096 + off);                                    \
      _Pragma("unroll") for (int m = 0; m < 4; m++) {                         \
        acc[m][n] = mfma16(afh[m], bfh, acc[m][n]);                           \
      }                                                                       \
    }                                                                         \
    __syncthreads();                                                          \
  }

// ---------------- prep: split f32 -> bf16 hi/lo (+ fused RoPE table) ------
__global__ __launch_bounds__(256) void k_prep(
    const float* __restrict__ x, const float* __restrict__ wq,
    const float* __restrict__ wk, const float* __restrict__ wv,
    const float* __restrict__ wo,
    u16* __restrict__ xh, u16* __restrict__ xl,
    u16* __restrict__ wh, u16* __restrict__ wl,
    float2* __restrict__ csn) {
  if (blockIdx.x >= 8192) {
    int idx = (blockIdx.x - 8192) * 256 + threadIdx.x;  // 65536 entries
    int p = idx >> 5, j = idx & 31;
    double invf = exp((double)(2 * j) * (-9.210340371976184 / 64.0));
    double ang = (double)p * invf;
    double kq = rint(ang * 0.15915494309189535);
    float a = (float)(ang - kq * 6.283185307179586);
    csn[idx] = make_float2(cosf(a), sinf(a));
    return;
  }
  int g = blockIdx.x * 256 + threadIdx.x;  // 4-element groups
  const float4* src;
  u16 *dh, *dl;
  int idx;
  bool wantlo = true;
  if (g < NX / 4) {
    src = (const float4*)x; dh = xh; dl = xl; idx = g;
  } else {
    int z = (g - NX / 4) / (NWEL / 4);
    int r = (g - NX / 4) % (NWEL / 4);
    src = (const float4*)(z == 0 ? wq : z == 1 ? wk : z == 2 ? wv : wo);
    dh = wh + (size_t)z * NWEL; dl = wl + (size_t)z * NWEL; idx = r;
    wantlo = (z < 2);
  }
  float4 v = src[idx];
  u16 h0 = f2bf(v.x), h1 = f2bf(v.y), h2 = f2bf(v.z), h3 = f2bf(v.w);
  ushort4 hv = make_ushort4(h0, h1, h2, h3);
  ((ushort4*)dh)[idx] = hv;
  if (wantlo) {
    ushort4 lv = make_ushort4(f2bf(v.x - bf2f(h0)), f2bf(v.y - bf2f(h1)),
                              f2bf(v.z - bf2f(h2)), f2bf(v.w - bf2f(h3)));
    ((ushort4*)dl)[idx] = lv;
  }
}

// ---------------- Q/K/V projection (merged, WORK-LIST dispatch) -----------
// 512 blocks; block w does tile w, and blocks w<256 also do tile w+512.
// Tiles 0..511 = Q/K (z 0,1); tiles 512..767 = V. Every CU keeps 2 resident
// blocks for the whole kernel (no 1-block/CU V tail round).
// z=0: Q (3-product split, rope, pre-scaled by 0.125*log2(e)), z=1: K (same,
// unscaled), z=2: V (1-product, transpose epilogue to vt[bh][dk][s]).
__global__ __launch_bounds__(256) void k_qkv(
    const u16* __restrict__ xh, const u16* __restrict__ xl,
    const u16* __restrict__ wh, const u16* __restrict__ wl,
    const int* __restrict__ tokpos, const float2* __restrict__ csn,
    u16* __restrict__ qh, u16* __restrict__ ql,
    u16* __restrict__ kh, u16* __restrict__ kl, u16* __restrict__ vt) {
  __shared__ __align__(16) u16 lds[32768];
  GEMM_PROLOGUE
#pragma unroll 1
  for (int ti = 0; ti < 2; ti++) {
    const int tile = (int)blockIdx.x + ti * 512;
    if (tile >= 768) break;
    const int z = tile >> 8;
    const int rem = tile & 255;
    const int t0 = (rem >> 3) * 128, j0 = (rem & 7) * 128;
    const int h0 = j0 >> 6;  // first head of this col-tile (2 heads/tile)
    const int b = t0 >> 11, s0 = t0 & 2047;
    f32x4 acc[4][4];
#pragma unroll
    for (int m = 0; m < 4; m++)
#pragma unroll
      for (int n = 0; n < 4; n++) acc[m][n] = f32x4{0.f, 0.f, 0.f, 0.f};

    if (z == 2) {
      const u16* wvh = wh + 2 * (size_t)NWEL;
      GEMM1_LOOP(xh, wvh, t0, j0)
      // transpose in LDS (swizzled), coalesced out to vt[bh][dk][s]
#pragma unroll
      for (int m = 0; m < 4; m++)
#pragma unroll
        for (int r = 0; r < 4; r++) {
          int rloc = wm * 64 + m * 16 + lg * 4 + r;
#pragma unroll
          for (int n = 0; n < 4; n++) {
            int cloc = wn * 64 + n * 16 + lr;
            lds[cloc * 128 + (rloc ^ ((cloc & 15) << 3))] = f2bf(acc[m][n][r]);
          }
        }
      __syncthreads();
#pragma unroll
      for (int i = 0; i < 8; i++) {
        int idx = tid + i * 256;
        int col = idx >> 4, rc = idx & 15;
        int4 v = *(int4*)(lds + col * 128 + ((rc * 8) ^ ((col & 15) << 3)));
        int h2 = col >> 6, dk = col & 63;
        size_t off =
            ((size_t)((b * NHEAD + h0 + h2) * 64 + dk)) * NSEQ + s0 + rc * 8;
        *(int4*)(vt + off) = v;
      }
    } else {
      const u16* Bh = wh + (size_t)z * NWEL;
      const u16* Bl = wl + (size_t)z * NWEL;
      GEMM3_LOOP(xh, xl, Bh, Bl, t0, j0)

      u16* dh = (z == 0) ? qh : kh;
      u16* dl = (z == 0) ? ql : kl;
      const float scl = (z == 0) ? 0.18033688011112042f : 1.0f;
      // rope in place, single dual-plane LDS pass (hi [0,16K), lo [16K,32K))
#pragma unroll
      for (int m = 0; m < 4; m++) {
#pragma unroll
        for (int r = 0; r < 4; r++) {
          int pos = tokpos[t0 + wm * 64 + m * 16 + lg * 4 + r];
          int rloc = wm * 64 + m * 16 + lg * 4 + r;
#pragma unroll
          for (int n = 0; n < 4; n++) {
            float val = acc[m][n][r];
            float nb = __shfl_xor(val, 1);
            int dk = (wn * 64 + n * 16 + lr) & 63;
            float2 cs = csn[pos * 32 + (dk >> 1)];
            float v = ((dk & 1) ? (nb * cs.y + val * cs.x)
                                : (val * cs.x - nb * cs.y)) * scl;
            int cloc = wn * 64 + n * 16 + lr;
            u16 hi = f2bf(v);
            lds[rloc * 128 + cloc] = hi;
            lds[16384 + rloc * 128 + cloc] = f2bf(v - bf2f(hi));
          }
        }
      }
      __syncthreads();
#pragma unroll
      for (int i = 0; i < 16; i++) {
        int idx = tid + i * 256;       // 0..4095 chunks of 8 u16 (2 planes)
        int plane = idx >> 11, i2 = idx & 2047;
        int r = i2 >> 4, cc = i2 & 15;
        int4 v = *(int4*)(lds + plane * 16384 + r * 128 + cc * 8);
        int h2 = cc >> 3, dk = (cc & 7) * 8;
        u16* dst = plane ? dl : dh;
        size_t off =
            ((size_t)((b * NHEAD + h0 + h2) * NSEQ + s0 + r)) * 64 + dk;
        *(int4*)(dst + off) = v;
      }
    }
    __syncthreads();  // LDS free before next tile's staging
  }
}

// ---------------- causal flash attention (QBLK=128, 8 waves on ONE tile) ---
// Validated round-13 structure: running-pointer staging, Q pre-scaled (log2
// domain), v_max3, defer-max, cvtpk, sp-LDS PV, setprio, XCD remap
// rank-major heavy-first.
#define ATT_STAGE(SEL)                                                        \
  _Pragma("unroll") for (int j_ = 0; j_ < 3; j_++) {                          \
    gload16(asrc[j_], adst[j_] + (SEL) * 4096);                               \
    asrc[j_] += astr[j_];                                                     \
  }

__global__ __launch_bounds__(512) void k_attn(
    const u16* __restrict__ qh, const u16* __restrict__ ql,
    const u16* __restrict__ kh, const u16* __restrict__ kl,
    const u16* __restrict__ vt, u16* __restrict__ ah) {
  __shared__ __align__(16) u16 skh[2][4096];
  __shared__ __align__(16) u16 skl[2][4096];
  __shared__ __align__(16) u16 svb[2][4096];
  __shared__ __align__(16) u16 sp[8192];
  const int tid = threadIdx.x, lane = tid & 63, w = tid >> 6;
  const int lr = lane & 15, lg = lane >> 4;
  const int fid = blockIdx.y * 16 + blockIdx.x;
  const int xcd = fid & 7, j = fid >> 3;
  const int rank = j >> 2, lbh = j & 3;
  const int bh = xcd * 4 + lbh;
  const int qt = 15 - rank;                // q-tile index (128 rows)
  const size_t base = (size_t)bh * NSEQ * 64;   // q/k: [bh][s][dk]
  const size_t vbase = (size_t)bh * 64 * NSEQ;  // vt:  [bh][dk][s]
  const int b = bh >> 4, h = bh & 15;
  const int q0 = qt * 128;
  const int nt = 2 * qt + 2;

  const int qrow_g = q0 + w * 16 + lr;
  bf16x8 qfh[2], qfl[2];
#pragma unroll
  for (int kk = 0; kk < 2; kk++) {
    qfh[kk] = ld16(qh + base + (size_t)qrow_g * 64 + kk * 32 + lg * 8);
    qfl[kk] = ld16(ql + base + (size_t)qrow_g * 64 + kk * 32 + lg * 8);
  }
  float mrun = -__builtin_inff(), lrun = 0.f;
  f32x4 oacc[4];
#pragma unroll
  for (int nf = 0; nf < 4; nf++) oacc[nf] = f32x4{0.f, 0.f, 0.f, 0.f};

  // ---- staging pointers: computed once, advanced by constant stride ----
  const u16* asrc[3];
  u16* adst[3];
  int astr[3];
#pragma unroll
  for (int j_ = 0; j_ < 3; j_++) {
    int seg_ = w * 3 + j_;
    int ten_ = seg_ >> 3, sub_ = seg_ & 7;
    int row_ = sub_ * 8 + (lane >> 3);
    int sc_ = ((lane & 7) * 8) ^ ((row_ & 7) * 8);  // u16 units
    adst[j_] = (ten_ == 0 ? &skh[0][0] : ten_ == 1 ? &skl[0][0] : &svb[0][0]) +
               sub_ * 512;
    astr[j_] = (ten_ == 2) ? 64 : 4096;
    asrc[j_] = (ten_ == 2)
                   ? vt + vbase + (size_t)row_ * NSEQ + sc_
                   : (ten_ == 0 ? kh : kl) + base + (size_t)row_ * 64 + sc_;
  }

  int sel = 0;
  ATT_STAGE(0)
  __syncthreads();
  for (int kt = 0; kt < nt; kt++) {
    if (kt + 1 < nt) { ATT_STAGE(sel ^ 1) }
    // ---- QK^T swapped: sacc[nf] holds S[k = nf*16+lg*4+r][q = lr],
    //      already in log2 domain (Q pre-scaled) ----
    f32x4 sacc[4];
#pragma unroll
    for (int nf = 0; nf < 4; nf++) sacc[nf] = f32x4{0.f, 0.f, 0.f, 0.f};
    __builtin_amdgcn_s_setprio(1);
#pragma unroll
    for (int nf = 0; nf < 4; nf++) {
      int krow = nf * 16 + lr;
      int swz = (krow & 7) * 8;
#pragma unroll
      for (int kk = 0; kk < 2; kk++) {
        int off = krow * 64 + ((kk * 32 + lg * 8) ^ swz);
        bf16x8 kfh = ld16(&skh[sel][0] + off);
        bf16x8 kfl = ld16(&skl[sel][0] + off);
        sacc[nf] = mfma16(kfh, qfh[kk], sacc[nf]);
        sacc[nf] = mfma16(kfl, qfh[kk], sacc[nf]);
        sacc[nf] = mfma16(kfh, qfl[kk], sacc[nf]);
      }
    }
    __builtin_amdgcn_s_setprio(0);
    // ---- per-lane softmax for q-row lr ----
    float sv[4][4], mm[4];
#pragma unroll
    for (int nf = 0; nf < 4; nf++) {
#pragma unroll
      for (int r = 0; r < 4; r++) sv[nf][r] = sacc[nf][r];
    }
    if (kt >= nt - 2) {  // diagonal spans the last two KV tiles
#pragma unroll
      for (int nf = 0; nf < 4; nf++)
#pragma unroll
        for (int r = 0; r < 4; r++) {
          int colg = kt * 64 + nf * 16 + lg * 4 + r;
          if (colg > qrow_g) sv[nf][r] = -__builtin_inff();
        }
    }
#pragma unroll
    for (int nf = 0; nf < 4; nf++)
      mm[nf] = fmaxf(max3f(sv[nf][0], sv[nf][1], sv[nf][2]), sv[nf][3]);
    float rmax = fmaxf(max3f(mm[0], mm[1], mm[2]), mm[3]);
    rmax = fmaxf(rmax, __shfl_xor(rmax, 16));
    rmax = fmaxf(rmax, __shfl_xor(rmax, 32));
    // defer-max (T13): rescale only when some row's max grew by > 8 (log2)
    float alpha = 1.f;
    bool resc = __any(rmax > mrun + 8.f);
    if (resc) {
      float mnew = fmaxf(mrun, rmax);
      alpha = exp2f(mrun - mnew);
      mrun = mnew;
      lrun *= alpha;
    }
    float p[4][4];
    float ss[4];
#pragma unroll
    for (int nf = 0; nf < 4; nf++) {
#pragma unroll
      for (int r = 0; r < 4; r++) p[nf][r] = exp2f(sv[nf][r] - mrun);
      ss[nf] = (p[nf][0] + p[nf][1]) + (p[nf][2] + p[nf][3]);
    }
    float rsum = (ss[0] + ss[1]) + (ss[2] + ss[3]);
    rsum += __shfl_xor(rsum, 16);
    rsum += __shfl_xor(rsum, 32);
    lrun += rsum;
    // ---- pack P -> sp[q = w*16+lr][k] (swizzled), 4x ds_write_b64 ----
    {
      int prow = w * 16 + lr;
      int swz = (prow & 7) * 8;
#pragma unroll
      for (int nf = 0; nf < 4; nf++) {
        u32 w0 = cvtpk(p[nf][0], p[nf][1]);
        u32 w1 = cvtpk(p[nf][2], p[nf][3]);
        int col = (nf * 16 + lg * 4) ^ swz;
        *(uint2*)(&sp[prow * 64 + col]) = make_uint2(w0, w1);
      }
    }
    // ---- rescale O by alpha of its own rows (q = lg*4+r), if needed ----
    if (resc) {
      float af0 = __shfl(alpha, lg * 4 + 0);
      float af1 = __shfl(alpha, lg * 4 + 1);
      float af2 = __shfl(alpha, lg * 4 + 2);
      float af3 = __shfl(alpha, lg * 4 + 3);
#pragma unroll
      for (int nf = 0; nf < 4; nf++) {
        oacc[nf][0] *= af0; oacc[nf][1] *= af1;
        oacc[nf][2] *= af2; oacc[nf][3] *= af3;
      }
    }
    // ---- PV: A = P (own wave's rows), B = V^T rows (d = nf*16+lr) ----
    {
      int prow = w * 16 + lr;
      int pswz = (prow & 7) * 8;
      __builtin_amdgcn_s_setprio(1);
#pragma unroll
      for (int kk = 0; kk < 2; kk++) {
        bf16x8 pa = ld16(&sp[prow * 64 + ((kk * 32 + lg * 8) ^ pswz)]);
#pragma unroll
        for (int nf = 0; nf < 4; nf++) {
          int vrow = nf * 16 + lr;
          bf16x8 vb2 = ld16(&svb[sel][0] + vrow * 64 +
                            ((kk * 32 + lg * 8) ^ ((vrow & 7) * 8)));
          oacc[nf] = mfma16(pa, vb2, oacc[nf]);
        }
      }
      __builtin_amdgcn_s_setprio(0);
    }
    __syncthreads();  // stage(sel^1) landed; all waves done reading sel
    sel ^= 1;
  }
  // ---- epilogue: normalize, bf16 store attn-out [token][1024] ----
  float inv = 1.0f / lrun;
  float iv0 = __shfl(inv, lg * 4 + 0);
  float iv1 = __shfl(inv, lg * 4 + 1);
  float iv2 = __shfl(inv, lg * 4 + 2);
  float iv3 = __shfl(inv, lg * 4 + 3);
#pragma unroll
  for (int r = 0; r < 4; r++) {
    float ivr = r == 0 ? iv0 : r == 1 ? iv1 : r == 2 ? iv2 : iv3;
    int row = q0 + w * 16 + lg * 4 + r;
    size_t toff = ((size_t)(b * NSEQ + row)) * NDIM + h * 64;
#pragma unroll
    for (int nf = 0; nf < 4; nf++) {
      ah[toff + nf * 16 + lr] = f2bf(oacc[nf][r] * ivr);
    }
  }
}

// ---------------- final projection: out = A * Wo^T (plain bf16, f32 store) -
__global__ __launch_bounds__(256) void k_out(
    const u16* __restrict__ ah, const u16* __restrict__ wh,
    float* __restrict__ out) {
  __shared__ __align__(16) u16 lds[16384];
  const int t0 = blockIdx.y * 128, j0 = blockIdx.x * 128;
  GEMM_PROLOGUE
  f32x4 acc[4][4];
#pragma unroll
  for (int m = 0; m < 4; m++)
#pragma unroll
    for (int n = 0; n < 4; n++) acc[m][n] = f32x4{0.f, 0.f, 0.f, 0.f};
  GEMM1_LOOP(ah, wh, t0, j0)
#pragma unroll
  for (int m = 0; m < 4; m++)
#pragma unroll
    for (int r = 0; r < 4; r++) {
      int row = t0 + wm * 64 + m * 16 + lg * 4 + r;
#pragma unroll
      for (int n = 0; n < 4; n++) {
        int col = j0 + wn * 64 + n * 16 + lr;
        out[(size_t)row * NDIM + col] = acc[m][n][r];
      }
    }
}

extern "C" void kernel_launch(void* const* d_in, const int* in_sizes, int n_in,
                              void* d_out, int out_size, void* d_ws, size_t ws_size,
                              hipStream_t stream) {
  (void)in_sizes; (void)n_in; (void)out_size; (void)ws_size;
  const float* x = (const float*)d_in[0];
  const int* tokpos = (const int*)d_in[1];
  const float* wq = (const float*)d_in[2];
  const float* wk = (const float*)d_in[3];
  const float* wv = (const float*)d_in[4];
  const float* wo = (const float*)d_in[5];
  float* out = (float*)d_out;

  u16* ws = (u16*)d_ws;
  u16* xh = ws;              // NX  (reused as attn-out after projections)
  u16* xl = xh + NX;         // NX
  u16* wh = xl + NX;         // 4*NWEL (q,k,v,o)
  u16* wl = wh + 4 * (size_t)NWEL;  // lo only valid for q,k
  u16* qh = wl + 4 * (size_t)NWEL;
  u16* ql = qh + NX;
  u16* kh = ql + NX;
  u16* kl = kh + NX;
  u16* vt = kl + NX;         // ends at 75.5 MB
  float2* csn = (float2*)(vt + NX);  // +512 KB rope table

  k_prep<<<dim3(8448), dim3(256), 0, stream>>>(x, wq, wk, wv, wo, xh, xl, wh,
                                               wl, csn);
  k_qkv<<<dim3(512), dim3(256), 0, stream>>>(xh, xl, wh, wl, tokpos, csn,
                                             qh, ql, kh, kl, vt);
  k_attn<<<dim3(16, 32), dim3(512), 0, stream>>>(qh, ql, kh, kl, vt, xh);
  k_out<<<dim3(8, 32), dim3(256), 0, stream>>>(xh, wh + 3 * (size_t)NWEL, out);
}

// Round 17
// 167.990 us; speedup vs baseline: 1.3243x; 1.3243x over previous
//
#include <hip/hip_runtime.h>

typedef unsigned short u16;
typedef unsigned int u32;
typedef __attribute__((ext_vector_type(8))) __bf16 bf16x8;
typedef __attribute__((ext_vector_type(4))) float f32x4;

#define NSEQ 2048
#define NDIM 1024
#define NHEAD 16
#define NTOK 4096
#define NX   4194304   /* NTOK*NDIM */
#define NWEL 1048576   /* NDIM*NDIM */

__device__ __forceinline__ u16 f2bf(float f) {
  unsigned u = __float_as_uint(f);
  return (u16)((u + 0x7fffu + ((u >> 16) & 1u)) >> 16);
}
__device__ __forceinline__ float bf2f(u16 h) {
  return __uint_as_float(((unsigned)h) << 16);
}
__device__ __forceinline__ bf16x8 ld16(const u16* p) {
  int4 v = *reinterpret_cast<const int4*>(p);
  return __builtin_bit_cast(bf16x8, v);
}
__device__ __forceinline__ f32x4 mfma16(bf16x8 a, bf16x8 b, f32x4 c) {
  return __builtin_amdgcn_mfma_f32_16x16x32_bf16(a, b, c, 0, 0, 0);
}
// packed f32x2 -> bf16x2 (RNE), one instruction (m214/m240-verified: lo=src0)
__device__ __forceinline__ u32 cvtpk(float lo, float hi) {
  u32 r;
  asm("v_cvt_pk_bf16_f32 %0, %1, %2" : "=v"(r) : "v"(lo), "v"(hi));
  return r;
}
// 3-input max, single instruction (T17)
__device__ __forceinline__ float max3f(float a, float b, float c) {
  float d;
  asm("v_max3_f32 %0, %1, %2, %3" : "=v"(d) : "v"(a), "v"(b), "v"(c));
  return d;
}
// async global->LDS, 16B per lane; LDS dest = wave-uniform base + lane*16
__device__ __forceinline__ void gload16(const u16* g, u16* l) {
  __builtin_amdgcn_global_load_lds(
      (const __attribute__((address_space(1))) void*)g,
      (__attribute__((address_space(3))) void*)l, 16, 0, 0);
}

// GEMM k-loops stay macro-expanded: round-2 post-mortem showed a function
// boundary around the accumulator array -> SROA failure -> acc in scratch.
// Falsified levers (do not retry): 3-deep counted-vmcnt (r11, neutral),
// single-buffer (r14, -27%), fp16 single-product projection (r15, absmax 472),
// work-list z-merge (r16, VGPR 256 -> -32%). The 2-barrier dbuf 128-tile loop
// with separate per-z dispatch below is the validated optimum (~700 TF).
#define GEMM_PROLOGUE                                                         \
  const int tid = threadIdx.x;                                                \
  const int lane = tid & 63, wid = tid >> 6;                                  \
  const int wm = wid >> 1, wn = wid & 1;                                      \
  const int lr = lane & 15, lg = lane >> 4;                                   \
  const int srow_ = tid >> 2;                                                 \
  const int sch_ = ((tid & 3) ^ ((tid >> 3) & 3)) * 8;                        \
  const int rsw_ = (lg ^ ((lr >> 1) & 3)) * 8;

#define STAGE3(BB, AH, AL, BH, BL, T0, J0, K0)                                \
  {                                                                           \
    u16* bb_ = (BB);                                                          \
    gload16(AH + (size_t)((T0) + srow_) * NDIM + (K0) + sch_, bb_ + tid * 8); \
    gload16(AH + (size_t)((T0) + 64 + srow_) * NDIM + (K0) + sch_,            \
            bb_ + 2048 + tid * 8);                                            \
    gload16(BH + (size_t)((J0) + srow_) * NDIM + (K0) + sch_,                 \
            bb_ + 4096 + tid * 8);                                            \
    gload16(BH + (size_t)((J0) + 64 + srow_) * NDIM + (K0) + sch_,            \
            bb_ + 6144 + tid * 8);                                            \
    gload16(AL + (size_t)((T0) + srow_) * NDIM + (K0) + sch_,                 \
            bb_ + 8192 + tid * 8);                                            \
    gload16(AL + (size_t)((T0) + 64 + srow_) * NDIM + (K0) + sch_,            \
            bb_ + 10240 + tid * 8);                                           \
    gload16(BL + (size_t)((J0) + srow_) * NDIM + (K0) + sch_,                 \
            bb_ + 12288 + tid * 8);                                           \
    gload16(BL + (size_t)((J0) + 64 + srow_) * NDIM + (K0) + sch_,            \
            bb_ + 14336 + tid * 8);                                           \
  }

#define GEMM3_LOOP(AH, AL, BH, BL, T0, J0)                                    \
  STAGE3(lds, AH, AL, BH, BL, T0, J0, 0)                                      \
  __syncthreads();                                                            \
  for (int k0 = 0; k0 < NDIM; k0 += 32) {                                     \
    u16* cb_ = lds + ((k0 >> 5) & 1) * 16384;                                 \
    if (k0 + 32 < NDIM) {                                                     \
      u16* nb_ = lds + ((((k0 >> 5) & 1) ^ 1) * 16384);                       \
      STAGE3(nb_, AH, AL, BH, BL, T0, J0, k0 + 32)                            \
    }                                                                         \
    bf16x8 afh[4], afl[4];                                                    \
    _Pragma("unroll") for (int m = 0; m < 4; m++) {                           \
      int off = (wm * 64 + m * 16 + lr) * 32 + rsw_;                          \
      afh[m] = ld16(cb_ + off);                                               \
      afl[m] = ld16(cb_ + 8192 + off);                                        \
    }                                                                         \
    _Pragma("unroll") for (int n = 0; n < 4; n++) {                           \
      int off = (wn * 64 + n * 16 + lr) * 32 + rsw_;                          \
      bf16x8 bfh = ld16(cb_ + 4096 + off);                                    \
      bf16x8 bfl = ld16(cb_ + 12288 + off);                                   \
      _Pragma("unroll") for (int m = 0; m < 4; m++) {                         \
        acc[m][n] = mfma16(afh[m], bfh, acc[m][n]);                           \
        acc[m][n] = mfma16(afh[m], bfl, acc[m][n]);                           \
        acc[m][n] = mfma16(afl[m], bfh, acc[m][n]);                           \
      }                                                                       \
    }                                                                         \
    __syncthreads();                                                          \
  }

#define STAGE1(BB, AH, BH, T0, J0, K0)                                        \
  {                                                                           \
    u16* bb_ = (BB);                                                          \
    gload16(AH + (size_t)((T0) + srow_) * NDIM + (K0) + sch_, bb_ + tid * 8); \
    gload16(AH + (size_t)((T0) + 64 + srow_) * NDIM + (K0) + sch_,            \
            bb_ + 2048 + tid * 8);                                            \
    gload16(BH + (size_t)((J0) + srow_) * NDIM + (K0) + sch_,                 \
            bb_ + 4096 + tid * 8);                                            \
    gload16(BH + (size_t)((J0) + 64 + srow_) * NDIM + (K0) + sch_,            \
            bb_ + 6144 + tid * 8);                                            \
  }

#define GEMM1_LOOP(AH, BH, T0, J0)                                            \
  STAGE1(lds, AH, BH, T0, J0, 0)                                              \
  __syncthreads();                                                            \
  for (int k0 = 0; k0 < NDIM; k0 += 32) {                                     \
    u16* cb_ = lds + ((k0 >> 5) & 1) * 8192;                                  \
    if (k0 + 32 < NDIM) {                                                     \
      u16* nb_ = lds + ((((k0 >> 5) & 1) ^ 1) * 8192);                        \
      STAGE1(nb_, AH, BH, T0, J0, k0 + 32)                                    \
    }                                                                         \
    bf16x8 afh[4];                                                            \
    _Pragma("unroll") for (int m = 0; m < 4; m++) {                           \
      int off = (wm * 64 + m * 16 + lr) * 32 + rsw_;                          \
      afh[m] = ld16(cb_ + off);                                               \
    }                                                                         \
    _Pragma("unroll") for (int n = 0; n < 4; n++) {                           \
      int off = (wn * 64 + n * 16 + lr) * 32 + rsw_;                          \
      bf16x8 bfh = ld16(cb_ + 4096 + off);                                    \
      _Pragma("unroll") for (int m = 0; m < 4; m++) {                         \
        acc[m][n] = mfma16(afh[m], bfh, acc[m][n]);                           \
      }                                                                       \
    }                                                                         \
    __syncthreads();                                                          \
  }

// ---------------- prep: split f32 -> bf16 hi/lo (+ fused RoPE table) ------
// Blocks >= 8192 compute the 2048x32 cos/sin table (was kernel k_tab).
__global__ __launch_bounds__(256) void k_prep(
    const float* __restrict__ x, const float* __restrict__ wq,
    const float* __restrict__ wk, const float* __restrict__ wv,
    const float* __restrict__ wo,
    u16* __restrict__ xh, u16* __restrict__ xl,
    u16* __restrict__ wh, u16* __restrict__ wl,
    float2* __restrict__ csn) {
  if (blockIdx.x >= 8192) {
    int idx = (blockIdx.x - 8192) * 256 + threadIdx.x;  // 65536 entries
    int p = idx >> 5, j = idx & 31;
    double invf = exp((double)(2 * j) * (-9.210340371976184 / 64.0));
    double ang = (double)p * invf;
    double kq = rint(ang * 0.15915494309189535);
    float a = (float)(ang - kq * 6.283185307179586);
    csn[idx] = make_float2(cosf(a), sinf(a));
    return;
  }
  int g = blockIdx.x * 256 + threadIdx.x;  // 4-element groups
  const float4* src;
  u16 *dh, *dl;
  int idx;
  bool wantlo = true;
  if (g < NX / 4) {
    src = (const float4*)x; dh = xh; dl = xl; idx = g;
  } else {
    int z = (g - NX / 4) / (NWEL / 4);
    int r = (g - NX / 4) % (NWEL / 4);
    src = (const float4*)(z == 0 ? wq : z == 1 ? wk : z == 2 ? wv : wo);
    dh = wh + (size_t)z * NWEL; dl = wl + (size_t)z * NWEL; idx = r;
    wantlo = (z < 2);
  }
  float4 v = src[idx];
  u16 h0 = f2bf(v.x), h1 = f2bf(v.y), h2 = f2bf(v.z), h3 = f2bf(v.w);
  ushort4 hv = make_ushort4(h0, h1, h2, h3);
  ((ushort4*)dh)[idx] = hv;
  if (wantlo) {
    ushort4 lv = make_ushort4(f2bf(v.x - bf2f(h0)), f2bf(v.y - bf2f(h1)),
                              f2bf(v.z - bf2f(h2)), f2bf(v.w - bf2f(h3)));
    ((ushort4*)dl)[idx] = lv;
  }
}

// ---------------- Q/K/V projection (merged, per-z dispatch) ----------------
// z=0: Q (3-product split, rope, pre-scaled by 0.125*log2(e)), z=1: K (same,
// unscaled), z=2: V (1-product, transpose epilogue to vt[bh][dk][s]).
// z=2 blocks dispatch last and overlap the Q/K tail.
__global__ __launch_bounds__(256) void k_qkv(
    const u16* __restrict__ xh, const u16* __restrict__ xl,
    const u16* __restrict__ wh, const u16* __restrict__ wl,
    const int* __restrict__ tokpos, const float2* __restrict__ csn,
    u16* __restrict__ qh, u16* __restrict__ ql,
    u16* __restrict__ kh, u16* __restrict__ kl, u16* __restrict__ vt) {
  __shared__ __align__(16) u16 lds[32768];
  const int z = blockIdx.z;
  const int t0 = blockIdx.y * 128, j0 = blockIdx.x * 128;
  const int h0 = j0 >> 6;  // first head of this col-tile (2 heads/tile)
  GEMM_PROLOGUE
  f32x4 acc[4][4];
#pragma unroll
  for (int m = 0; m < 4; m++)
#pragma unroll
    for (int n = 0; n < 4; n++) acc[m][n] = f32x4{0.f, 0.f, 0.f, 0.f};
  const int b = t0 >> 11, s0 = t0 & 2047;

  if (z == 2) {
    const u16* wvh = wh + 2 * (size_t)NWEL;
    GEMM1_LOOP(xh, wvh, t0, j0)
    // transpose in LDS (swizzled), coalesced out to vt[bh][dk][s]
#pragma unroll
    for (int m = 0; m < 4; m++)
#pragma unroll
      for (int r = 0; r < 4; r++) {
        int rloc = wm * 64 + m * 16 + lg * 4 + r;
#pragma unroll
        for (int n = 0; n < 4; n++) {
          int cloc = wn * 64 + n * 16 + lr;
          lds[cloc * 128 + (rloc ^ ((cloc & 15) << 3))] = f2bf(acc[m][n][r]);
        }
      }
    __syncthreads();
#pragma unroll
    for (int i = 0; i < 8; i++) {
      int idx = tid + i * 256;
      int col = idx >> 4, rc = idx & 15;
      int4 v = *(int4*)(lds + col * 128 + ((rc * 8) ^ ((col & 15) << 3)));
      int h2 = col >> 6, dk = col & 63;
      size_t off =
          ((size_t)((b * NHEAD + h0 + h2) * 64 + dk)) * NSEQ + s0 + rc * 8;
      *(int4*)(vt + off) = v;
    }
    return;
  }

  const u16* Bh = wh + (size_t)z * NWEL;
  const u16* Bl = wl + (size_t)z * NWEL;
  GEMM3_LOOP(xh, xl, Bh, Bl, t0, j0)

  u16* dh = (z == 0) ? qh : kh;
  u16* dl = (z == 0) ? ql : kl;
  const float scl = (z == 0) ? 0.18033688011112042f : 1.0f;
  // rope in place, single dual-plane LDS pass (hi [0,16K), lo [16K,32K))
#pragma unroll
  for (int m = 0; m < 4; m++) {
#pragma unroll
    for (int r = 0; r < 4; r++) {
      int pos = tokpos[t0 + wm * 64 + m * 16 + lg * 4 + r];
      int rloc = wm * 64 + m * 16 + lg * 4 + r;
#pragma unroll
      for (int n = 0; n < 4; n++) {
        float val = acc[m][n][r];
        float nb = __shfl_xor(val, 1);
        int dk = (wn * 64 + n * 16 + lr) & 63;
        float2 cs = csn[pos * 32 + (dk >> 1)];
        float v = ((dk & 1) ? (nb * cs.y + val * cs.x)
                            : (val * cs.x - nb * cs.y)) * scl;
        int cloc = wn * 64 + n * 16 + lr;
        u16 hi = f2bf(v);
        lds[rloc * 128 + cloc] = hi;
        lds[16384 + rloc * 128 + cloc] = f2bf(v - bf2f(hi));
      }
    }
  }
  __syncthreads();
#pragma unroll
  for (int i = 0; i < 16; i++) {
    int idx = tid + i * 256;       // 0..4095 chunks of 8 u16 (2 planes)
    int plane = idx >> 11, i2 = idx & 2047;
    int r = i2 >> 4, cc = i2 & 15;
    int4 v = *(int4*)(lds + plane * 16384 + r * 128 + cc * 8);
    int h2 = cc >> 3, dk = (cc & 7) * 8;
    u16* dst = plane ? dl : dh;
    size_t off = ((size_t)((b * NHEAD + h0 + h2) * NSEQ + s0 + r)) * 64 + dk;
    *(int4*)(dst + off) = v;
  }
}

// ---------------- causal flash attention (QBLK=128, 8 waves on ONE tile) ---
// Each block owns ONE 128-row q-tile; all 8 waves (16 rows each) busy every
// iteration; nt = 2*qt+2 KV tiles. Causal mask on last TWO tiles. Heavy
// tiles dispatch first (rank-major within XCD chunks).
#define ATT_STAGE(SEL)                                                        \
  _Pragma("unroll") for (int j_ = 0; j_ < 3; j_++) {                          \
    gload16(asrc[j_], adst[j_] + (SEL) * 4096);                               \
    asrc[j_] += astr[j_];                                                     \
  }

__global__ __launch_bounds__(512) void k_attn(
    const u16* __restrict__ qh, const u16* __restrict__ ql,
    const u16* __restrict__ kh, const u16* __restrict__ kl,
    const u16* __restrict__ vt, u16* __restrict__ ah) {
  __shared__ __align__(16) u16 skh[2][4096];
  __shared__ __align__(16) u16 skl[2][4096];
  __shared__ __align__(16) u16 svb[2][4096];
  __shared__ __align__(16) u16 sp[8192];
  const int tid = threadIdx.x, lane = tid & 63, w = tid >> 6;
  const int lr = lane & 15, lg = lane >> 4;
  const int fid = blockIdx.y * 16 + blockIdx.x;
  const int xcd = fid & 7, j = fid >> 3;
  const int rank = j >> 2, lbh = j & 3;
  const int bh = xcd * 4 + lbh;
  const int qt = 15 - rank;                // q-tile index (128 rows)
  const size_t base = (size_t)bh * NSEQ * 64;   // q/k: [bh][s][dk]
  const size_t vbase = (size_t)bh * 64 * NSEQ;  // vt:  [bh][dk][s]
  const int b = bh >> 4, h = bh & 15;
  const int q0 = qt * 128;
  const int nt = 2 * qt + 2;

  const int qrow_g = q0 + w * 16 + lr;
  bf16x8 qfh[2], qfl[2];
#pragma unroll
  for (int kk = 0; kk < 2; kk++) {
    qfh[kk] = ld16(qh + base + (size_t)qrow_g * 64 + kk * 32 + lg * 8);
    qfl[kk] = ld16(ql + base + (size_t)qrow_g * 64 + kk * 32 + lg * 8);
  }
  float mrun = -__builtin_inff(), lrun = 0.f;
  f32x4 oacc[4];
#pragma unroll
  for (int nf = 0; nf < 4; nf++) oacc[nf] = f32x4{0.f, 0.f, 0.f, 0.f};

  // ---- staging pointers: computed once, advanced by constant stride ----
  const u16* asrc[3];
  u16* adst[3];
  int astr[3];
#pragma unroll
  for (int j_ = 0; j_ < 3; j_++) {
    int seg_ = w * 3 + j_;
    int ten_ = seg_ >> 3, sub_ = seg_ & 7;
    int row_ = sub_ * 8 + (lane >> 3);
    int sc_ = ((lane & 7) * 8) ^ ((row_ & 7) * 8);  // u16 units
    adst[j_] = (ten_ == 0 ? &skh[0][0] : ten_ == 1 ? &skl[0][0] : &svb[0][0]) +
               sub_ * 512;
    astr[j_] = (ten_ == 2) ? 64 : 4096;
    asrc[j_] = (ten_ == 2)
                   ? vt + vbase + (size_t)row_ * NSEQ + sc_
                   : (ten_ == 0 ? kh : kl) + base + (size_t)row_ * 64 + sc_;
  }

  int sel = 0;
  ATT_STAGE(0)
  __syncthreads();
  for (int kt = 0; kt < nt; kt++) {
    if (kt + 1 < nt) { ATT_STAGE(sel ^ 1) }
    // ---- QK^T swapped: sacc[nf] holds S[k = nf*16+lg*4+r][q = lr],
    //      already in log2 domain (Q pre-scaled) ----
    f32x4 sacc[4];
#pragma unroll
    for (int nf = 0; nf < 4; nf++) sacc[nf] = f32x4{0.f, 0.f, 0.f, 0.f};
    __builtin_amdgcn_s_setprio(1);
#pragma unroll
    for (int nf = 0; nf < 4; nf++) {
      int krow = nf * 16 + lr;
      int swz = (krow & 7) * 8;
#pragma unroll
      for (int kk = 0; kk < 2; kk++) {
        int off = krow * 64 + ((kk * 32 + lg * 8) ^ swz);
        bf16x8 kfh = ld16(&skh[sel][0] + off);
        bf16x8 kfl = ld16(&skl[sel][0] + off);
        sacc[nf] = mfma16(kfh, qfh[kk], sacc[nf]);
        sacc[nf] = mfma16(kfl, qfh[kk], sacc[nf]);
        sacc[nf] = mfma16(kfh, qfl[kk], sacc[nf]);
      }
    }
    __builtin_amdgcn_s_setprio(0);
    // ---- per-lane softmax for q-row lr ----
    float sv[4][4], mm[4];
#pragma unroll
    for (int nf = 0; nf < 4; nf++) {
#pragma unroll
      for (int r = 0; r < 4; r++) sv[nf][r] = sacc[nf][r];
    }
    if (kt >= nt - 2) {  // diagonal spans the last two KV tiles
#pragma unroll
      for (int nf = 0; nf < 4; nf++)
#pragma unroll
        for (int r = 0; r < 4; r++) {
          int colg = kt * 64 + nf * 16 + lg * 4 + r;
          if (colg > qrow_g) sv[nf][r] = -__builtin_inff();
        }
    }
#pragma unroll
    for (int nf = 0; nf < 4; nf++)
      mm[nf] = fmaxf(max3f(sv[nf][0], sv[nf][1], sv[nf][2]), sv[nf][3]);
    float rmax = fmaxf(max3f(mm[0], mm[1], mm[2]), mm[3]);
    rmax = fmaxf(rmax, __shfl_xor(rmax, 16));
    rmax = fmaxf(rmax, __shfl_xor(rmax, 32));
    // defer-max (T13): rescale only when some row's max grew by > 8 (log2)
    float alpha = 1.f;
    bool resc = __any(rmax > mrun + 8.f);
    if (resc) {
      float mnew = fmaxf(mrun, rmax);
      alpha = exp2f(mrun - mnew);
      mrun = mnew;
      lrun *= alpha;
    }
    float p[4][4];
    float ss[4];
#pragma unroll
    for (int nf = 0; nf < 4; nf++) {
#pragma unroll
      for (int r = 0; r < 4; r++) p[nf][r] = exp2f(sv[nf][r] - mrun);
      ss[nf] = (p[nf][0] + p[nf][1]) + (p[nf][2] + p[nf][3]);
    }
    float rsum = (ss[0] + ss[1]) + (ss[2] + ss[3]);
    rsum += __shfl_xor(rsum, 16);
    rsum += __shfl_xor(rsum, 32);
    lrun += rsum;
    // ---- pack P -> sp[q = w*16+lr][k] (swizzled), 4x ds_write_b64 ----
    {
      int prow = w * 16 + lr;
      int swz = (prow & 7) * 8;
#pragma unroll
      for (int nf = 0; nf < 4; nf++) {
        u32 w0 = cvtpk(p[nf][0], p[nf][1]);
        u32 w1 = cvtpk(p[nf][2], p[nf][3]);
        int col = (nf * 16 + lg * 4) ^ swz;
        *(uint2*)(&sp[prow * 64 + col]) = make_uint2(w0, w1);
      }
    }
    // ---- rescale O by alpha of its own rows (q = lg*4+r), if needed ----
    if (resc) {
      float af0 = __shfl(alpha, lg * 4 + 0);
      float af1 = __shfl(alpha, lg * 4 + 1);
      float af2 = __shfl(alpha, lg * 4 + 2);
      float af3 = __shfl(alpha, lg * 4 + 3);
#pragma unroll
      for (int nf = 0; nf < 4; nf++) {
        oacc[nf][0] *= af0; oacc[nf][1] *= af1;
        oacc[nf][2] *= af2; oacc[nf][3] *= af3;
      }
    }
    // ---- PV: A = P (own wave's rows), B = V^T rows (d = nf*16+lr) ----
    {
      int prow = w * 16 + lr;
      int pswz = (prow & 7) * 8;
      __builtin_amdgcn_s_setprio(1);
#pragma unroll
      for (int kk = 0; kk < 2; kk++) {
        bf16x8 pa = ld16(&sp[prow * 64 + ((kk * 32 + lg * 8) ^ pswz)]);
#pragma unroll
        for (int nf = 0; nf < 4; nf++) {
          int vrow = nf * 16 + lr;
          bf16x8 vb2 = ld16(&svb[sel][0] + vrow * 64 +
                            ((kk * 32 + lg * 8) ^ ((vrow & 7) * 8)));
          oacc[nf] = mfma16(pa, vb2, oacc[nf]);
        }
      }
      __builtin_amdgcn_s_setprio(0);
    }
    __syncthreads();  // stage(sel^1) landed; all waves done reading sel
    sel ^= 1;
  }
  // ---- epilogue: normalize, bf16 store attn-out [token][1024] ----
  float inv = 1.0f / lrun;
  float iv0 = __shfl(inv, lg * 4 + 0);
  float iv1 = __shfl(inv, lg * 4 + 1);
  float iv2 = __shfl(inv, lg * 4 + 2);
  float iv3 = __shfl(inv, lg * 4 + 3);
#pragma unroll
  for (int r = 0; r < 4; r++) {
    float ivr = r == 0 ? iv0 : r == 1 ? iv1 : r == 2 ? iv2 : iv3;
    int row = q0 + w * 16 + lg * 4 + r;
    size_t toff = ((size_t)(b * NSEQ + row)) * NDIM + h * 64;
#pragma unroll
    for (int nf = 0; nf < 4; nf++) {
      ah[toff + nf * 16 + lr] = f2bf(oacc[nf][r] * ivr);
    }
  }
}

// ---------------- final projection: out = A * Wo^T (plain bf16, f32 store) -
__global__ __launch_bounds__(256) void k_out(
    const u16* __restrict__ ah, const u16* __restrict__ wh,
    float* __restrict__ out) {
  __shared__ __align__(16) u16 lds[16384];
  const int t0 = blockIdx.y * 128, j0 = blockIdx.x * 128;
  GEMM_PROLOGUE
  f32x4 acc[4][4];
#pragma unroll
  for (int m = 0; m < 4; m++)
#pragma unroll
    for (int n = 0; n < 4; n++) acc[m][n] = f32x4{0.f, 0.f, 0.f, 0.f};
  GEMM1_LOOP(ah, wh, t0, j0)
#pragma unroll
  for (int m = 0; m < 4; m++)
#pragma unroll
    for (int r = 0; r < 4; r++) {
      int row = t0 + wm * 64 + m * 16 + lg * 4 + r;
#pragma unroll
      for (int n = 0; n < 4; n++) {
        int col = j0 + wn * 64 + n * 16 + lr;
        out[(size_t)row * NDIM + col] = acc[m][n][r];
      }
    }
}

extern "C" void kernel_launch(void* const* d_in, const int* in_sizes, int n_in,
                              void* d_out, int out_size, void* d_ws, size_t ws_size,
                              hipStream_t stream) {
  (void)in_sizes; (void)n_in; (void)out_size; (void)ws_size;
  const float* x = (const float*)d_in[0];
  const int* tokpos = (const int*)d_in[1];
  const float* wq = (const float*)d_in[2];
  const float* wk = (const float*)d_in[3];
  const float* wv = (const float*)d_in[4];
  const float* wo = (const float*)d_in[5];
  float* out = (float*)d_out;

  u16* ws = (u16*)d_ws;
  u16* xh = ws;              // NX  (reused as attn-out after projections)
  u16* xl = xh + NX;         // NX
  u16* wh = xl + NX;         // 4*NWEL (q,k,v,o)
  u16* wl = wh + 4 * (size_t)NWEL;  // lo only valid for q,k
  u16* qh = wl + 4 * (size_t)NWEL;
  u16* ql = qh + NX;
  u16* kh = ql + NX;
  u16* kl = kh + NX;
  u16* vt = kl + NX;         // ends at 75.5 MB
  float2* csn = (float2*)(vt + NX);  // +512 KB rope table

  k_prep<<<dim3(8448), dim3(256), 0, stream>>>(x, wq, wk, wv, wo, xh, xl, wh,
                                               wl, csn);
  k_qkv<<<dim3(8, 32, 3), dim3(256), 0, stream>>>(xh, xl, wh, wl, tokpos, csn,
                                                  qh, ql, kh, kl, vt);
  k_attn<<<dim3(16, 32), dim3(512), 0, stream>>>(qh, ql, kh, kl, vt, xh);
  k_out<<<dim3(8, 32), dim3(256), 0, stream>>>(xh, wh + 3 * (size_t)NWEL, out);
}